// Round 1
// baseline (696.336 us; speedup 1.0000x reference)
//
#include <hip/hip_runtime.h>

typedef _Float16 half_t;
typedef _Float16 half8 __attribute__((ext_vector_type(8)));
typedef float f32x4 __attribute__((ext_vector_type(4)));

#define B_TOT    262144
#define PRED_LEN 12
#define NBLK     (B_TOT/64)

// half-element offsets inside d_ws
#define OFF_WHH 0            // 24 ct * 4 chunks * 64 lanes * 8  = 49152 halfs
#define OFF_WC  49152        // 24 ct * 64 lanes * 8             = 12288
#define OFF_W1S 61440        // 4*4*64*8                          = 8192
#define OFF_W1H 69632        // 4*4*64*8                          = 8192
#define OFF_W2  77824        // 2*64*8                            = 1024
#define HALFS_TOTAL 78848
#define PREP_TOTAL  79104    // + 256 small floats

#define A_RZ (-1.44269504f)  // -log2(e): folded so sigmoid(x)=rcp(1+exp2(acc))
#define A_N  (2.88539008f)   // 2*log2(e): folded so tanh(y)=1-2*rcp(exp2(acc)+1)

#define MFMA16(a,b,c) __builtin_amdgcn_mfma_f32_16x16x32_f16((a),(b),(c),0,0,0)

__device__ __forceinline__ float exp2f_(float x){ return __builtin_amdgcn_exp2f(x); }
__device__ __forceinline__ float rcpf_(float x){ return __builtin_amdgcn_rcpf(x); }

// ------------------------------------------------------------------
// prep kernel: fold emb into W_ih, bake biases+log2 scales, emit all
// weights as fp16 MFMA B-fragments (frag-linear, lane-contiguous).
// ------------------------------------------------------------------
__global__ void prep_kernel(const float* __restrict__ emb_W, const float* __restrict__ emb_b,
                            const float* __restrict__ W_ih, const float* __restrict__ W_hh,
                            const float* __restrict__ b_ih, const float* __restrict__ b_hh,
                            const float* __restrict__ W1,   const float* __restrict__ W2,
                            const float* __restrict__ b1,   const float* __restrict__ b2,
                            half_t* __restrict__ wsh, float* __restrict__ wsf) {
  int f = blockIdx.x*256 + threadIdx.x;
  if (f >= PREP_TOTAL) return;
  if (f < OFF_WC) {
    // W_hh fragments: ct = g*8+jb, B[col=g*128+jb*16+(l&15)][k=c*32+(l>>4)*8+e]
    int e = f&7, l = (f>>3)&63, c = (f>>9)&3, ct = f>>11;
    int g = ct>>3, jb = ct&7;
    int col = g*128 + jb*16 + (l&15);
    int k = c*32 + (l>>4)*8 + e;
    float a = (g<2) ? A_RZ : A_N;
    wsh[f] = (half_t)(a * W_hh[col*128 + k]);
  } else if (f < OFF_W1S) {
    // folded input-GEMM fragments (K=32 chunk): lanes 0-15 = hi rows (Wc*64),
    // lanes 16-31 = lo rows (Wc*64/2048), lanes 32-47 = bias at e==0, rest 0
    int ff = f - OFF_WC;
    int e = ff&7, l = (ff>>3)&63, ct = ff>>9;
    int g = ct>>3, jb = ct&7;
    int col = g*128 + jb*16 + (l&15);
    int sub = l>>4;
    float a = (g<2) ? A_RZ : A_N;
    float v = 0.f;
    if (sub <= 1) {
      float wc = 0.f;
      for (int m=0;m<128;++m) wc = fmaf(W_ih[col*128+m], emb_W[m*8+e], wc);
      v = a * 64.f * wc;
      if (sub==1) v *= (1.f/2048.f);
    } else if (sub==2 && e==0) {
      float bi = b_ih[col];
      for (int m=0;m<128;++m) bi = fmaf(W_ih[col*128+m], emb_b[m], bi);
      if (g<2) bi += b_hh[col];      // n-gate keeps b_hh separate (multiplied by r)
      v = a * bi;
    }
    wsh[f] = (half_t)v;
  } else if (f < OFF_W1H) {
    int ff = f - OFF_W1S;
    int e = ff&7, l=(ff>>3)&63, c=(ff>>9)&3, ct=ff>>11;
    int col = ct*16 + (l&15);
    int k = c*32 + (l>>4)*8 + e;
    wsh[f] = (half_t)W1[col*256 + 128 + k];   // social half
  } else if (f < OFF_W2) {
    int ff = f - OFF_W1H;
    int e = ff&7, l=(ff>>3)&63, c=(ff>>9)&3, ct=ff>>11;
    int col = ct*16 + (l&15);
    int k = c*32 + (l>>4)*8 + e;
    wsh[f] = (half_t)W1[col*256 + k];         // h half
  } else if (f < HALFS_TOTAL) {
    int ff = f - OFF_W2;
    int e = ff&7, l=(ff>>3)&63, c = ff>>9;
    int col = l&15;
    int k = c*32 + (l>>4)*8 + e;
    wsh[f] = (half_t)((col<4) ? W2[col*64 + k] : 0.f);
  } else {
    int ff = f - HALFS_TOTAL;
    float v = 0.f;
    if (ff < 64) v = b1[ff];
    else if (ff < 192) v = A_N * b_hh[256 + (ff-64)];
    else if (ff < 196) v = b2[ff-192];
    wsf[ff] = v;
  }
}

// hi/lo fp16 split of obs value (scaled 2^-6; residual *2^11)
__device__ __forceinline__ void write_split(half_t* obsplit, int row, int s, float v){
  float scv = v * 0.015625f;
  half_t hi = (half_t)scv;
  float lo = (scv - (float)hi) * 2048.0f;
  obsplit[row*16 + s]     = hi;
  obsplit[row*16 + 8 + s] = (half_t)lo;
}

// stage a [64][128] fp32 global tile into swizzled fp16 A-layout LDS tile
__device__ __forceinline__ void stage_tile(const float* __restrict__ src, half_t* htile,
                                           int b0, int tid){
  int row = tid>>3, cg = (tid&7)*16;
  const float* s = src + (size_t)(b0+row)*128 + cg;
  half8 p0, p1;
#pragma unroll
  for (int i=0;i<8;++i) p0[i] = (half_t)s[i];
#pragma unroll
  for (int i=0;i<8;++i) p1[i] = (half_t)s[8+i];
  int base = cg>>3;
  *(half8*)&htile[row*128 + (( base    ^ (row&15))<<3)] = p0;
  *(half8*)&htile[row*128 + (((base+1) ^ (row&15))<<3)] = p1;
}

// ------------------------------------------------------------------
// persistent decoder: 64 batch rows per block, 12 steps, h in LDS fp16
// ------------------------------------------------------------------
__global__ __launch_bounds__(512, 2)
void decoder_kernel(const float* __restrict__ xy, const float* __restrict__ dxdy,
                    const float* __restrict__ social, const float* __restrict__ h0,
                    const half_t* __restrict__ wsh, const float* __restrict__ wsf,
                    float* __restrict__ out) {
  __shared__ half_t htile[64*128];    // h (and social during init), XOR-swizzled slots
  __shared__ half_t w1h_lds[8192];    // W1h fragments
  __shared__ half_t z1t[64*64];       // z1 fp16 A-layout, swizzled
  __shared__ half_t obsplit[64*16];   // obs hi/lo split
  __shared__ float  dxdyt[64*4];

  const int tid = threadIdx.x;
  const int wid = tid>>6, lane = tid&63;
  const int l15 = lane&15, l4 = lane>>4;
  const int b0 = blockIdx.x*64;
  const int jq = wid&3, mp = wid>>2;       // phase-A: Mtiles {2mp,2mp+1}, jbs {2jq,2jq+1}

  // ---- resident weight fragments (per-wave, loop-invariant) ----
  half8 Bg[2][3][4], Bi[2][3];
#pragma unroll
  for (int j2=0;j2<2;++j2){
    int jb = jq*2+j2;
#pragma unroll
    for (int g=0; g<3; ++g){
      int ct = g*8+jb;
#pragma unroll
      for (int c=0;c<4;++c)
        Bg[j2][g][c] = *(const half8*)(wsh + OFF_WHH + ((size_t)(ct*4+c)*64 + lane)*8);
      Bi[j2][g] = *(const half8*)(wsh + OFF_WC + ((size_t)ct*64 + lane)*8);
    }
  }
  float bhn_s2[2];
#pragma unroll
  for (int j2=0;j2<2;++j2) bhn_s2[j2] = wsf[64 + (jq*2+j2)*16 + l15];
  half8 W2f[2];
#pragma unroll
  for (int c=0;c<2;++c) W2f[c] = *(const half8*)(wsh + OFF_W2 + ((size_t)c*64+lane)*8);
  float b2l = (l15<4) ? wsf[192+l15] : 0.f;

  // copy W1h fragments to LDS (frag-linear)
  for (int i = tid; i < 1024; i += 512)
    *(half8*)&w1h_lds[i*8] = *(const half8*)(wsh + OFF_W1H + (size_t)i*8);

  // ---- stage social, compute s_contrib (kept in registers) ----
  stage_tile(social, htile, b0, tid);
  __syncthreads();

  float sc[2][4];
  {
    int Mt = wid>>1;
    int arow = Mt*16 + l15;
    half8 ha[4];
#pragma unroll
    for (int c=0;c<4;++c){
      int slot = (c*4 + l4) ^ (arow&15);
      ha[c] = *(const half8*)&htile[arow*128 + slot*8];
    }
#pragma unroll
    for (int c2=0;c2<2;++c2){
      int ct = (wid&1)*2 + c2;
      f32x4 acc = {0.f,0.f,0.f,0.f};
#pragma unroll
      for (int c=0;c<4;++c){
        half8 bw = *(const half8*)(wsh + OFF_W1S + ((size_t)(ct*4+c)*64 + lane)*8);
        acc = MFMA16(ha[c], bw, acc);
      }
      float b1v = wsf[ct*16 + l15];
#pragma unroll
      for (int r=0;r<4;++r) sc[c2][r] = acc[r] + b1v;
    }
  }
  __syncthreads();

  // ---- stage h0, init obs split + per-thread obs master ----
  stage_tile(h0, htile, b0, tid);
  float obs_x = 0.f, obs_w = 0.f;
  if (tid < 256) {
    int row = tid>>2, q = tid&3;
    size_t gb = (size_t)(b0+row)*4;
    if (q < 2) {
      obs_x = xy[gb + q];
      obs_w = xy[gb + q + 2];
      write_split(obsplit, row, q,   obs_x);
      write_split(obsplit, row, q+2, obs_w);
    } else {
      int c0 = (q-2)*2;
      float d0 = dxdy[gb + c0], d1 = dxdy[gb + c0 + 1];
      write_split(obsplit, row, 4+c0, d0);
      write_split(obsplit, row, 5+c0, d1);
    }
  }
  __syncthreads();

  // ---- h_old register copy (same (row,col) this lane updates) ----
  float hq[2][2][4];
#pragma unroll
  for (int mt2=0;mt2<2;++mt2)
#pragma unroll
    for (int j2=0;j2<2;++j2){
      int col = (jq*2+j2)*16 + l15;
#pragma unroll
      for (int r=0;r<4;++r){
        int hrow = (mp*2+mt2)*16 + l4*4 + r;
        hq[mt2][j2][r] = (float)htile[hrow*128 + (((col>>3)^(hrow&15))<<3) + (col&7)];
      }
    }

  float* out0 = out;
  float* out1 = out + (size_t)PRED_LEN*B_TOT*4;

#pragma unroll 1
  for (int t=0; t<PRED_LEN; ++t) {
    // ---------------- Phase A1: gates + h update (registers) ----------------
#pragma unroll
    for (int mt2=0; mt2<2; ++mt2) {
      int Mt = mp*2+mt2;
      int arow = Mt*16 + l15;
      half8 ha[4];
#pragma unroll
      for (int c=0;c<4;++c){
        int slot = (c*4 + l4) ^ (arow & 15);
        ha[c] = *(const half8*)&htile[arow*128 + slot*8];
      }
      half8 oa = {0,0,0,0,0,0,0,0};
      if (lane < 32)      oa = *(const half8*)&obsplit[arow*16 + l4*8];
      else if (lane < 48) oa[0] = (half_t)1.f;   // multiplies baked bias row
#pragma unroll
      for (int j2=0;j2<2;++j2){
        f32x4 ar={0.f,0.f,0.f,0.f}, az={0.f,0.f,0.f,0.f};
        f32x4 ahn={0.f,0.f,0.f,0.f}, ain={0.f,0.f,0.f,0.f};
#pragma unroll
        for (int c=0;c<4;++c){
          ar  = MFMA16(ha[c], Bg[j2][0][c], ar);
          az  = MFMA16(ha[c], Bg[j2][1][c], az);
          ahn = MFMA16(ha[c], Bg[j2][2][c], ahn);
        }
        ar  = MFMA16(oa, Bi[j2][0], ar);
        az  = MFMA16(oa, Bi[j2][1], az);
        ain = MFMA16(oa, Bi[j2][2], ain);
#pragma unroll
        for (int r=0;r<4;++r){
          float R  = rcpf_(1.f + exp2f_(ar[r]));            // sigmoid (scale folded)
          float Z  = rcpf_(1.f + exp2f_(az[r]));
          float np = fmaf(R, ahn[r] + bhn_s2[j2], ain[r]);  // 2*log2e*(i_n + r*h_n)
          float N  = 1.f - 2.f*rcpf_(exp2f_(np) + 1.f);     // tanh
          float ho = hq[mt2][j2][r];
          hq[mt2][j2][r] = N + Z*(ho - N);
        }
      }
    }
    __syncthreads();
    // ---------------- Phase A2: publish h_new to LDS ----------------
#pragma unroll
    for (int mt2=0;mt2<2;++mt2)
#pragma unroll
      for (int j2=0;j2<2;++j2){
        int col = (jq*2+j2)*16 + l15;
#pragma unroll
        for (int r=0;r<4;++r){
          int hrow = (mp*2+mt2)*16 + l4*4 + r;
          htile[hrow*128 + (((col>>3)^(hrow&15))<<3) + (col&7)] = (half_t)hq[mt2][j2][r];
        }
      }
    __syncthreads();
    // ---------------- Phase B: z1 = leaky(h@W1h^T + s_contrib) ----------------
    {
      int Mt = wid>>1;
      int arow = Mt*16 + l15;
      half8 ha[4];
#pragma unroll
      for (int c=0;c<4;++c){
        int slot = (c*4+l4) ^ (arow&15);
        ha[c] = *(const half8*)&htile[arow*128 + slot*8];
      }
#pragma unroll
      for (int c2=0;c2<2;++c2){
        int ct = (wid&1)*2+c2;
        f32x4 acc={0.f,0.f,0.f,0.f};
#pragma unroll
        for (int c=0;c<4;++c){
          half8 bw = *(const half8*)&w1h_lds[((ct*4+c)*64 + lane)*8];
          acc = MFMA16(ha[c], bw, acc);
        }
        int col = ct*16 + l15;
#pragma unroll
        for (int r=0;r<4;++r){
          int zrow = Mt*16 + l4*4 + r;
          float v = acc[r] + sc[c2][r];
          v = fmaxf(v, 0.01f*v);
          z1t[zrow*64 + (((col>>3)^(zrow&7))<<3) + (col&7)] = (half_t)v;
        }
      }
    }
    __syncthreads();
    // ---------------- Phase C1: dxdy = leaky(z1@W2^T + b2) ----------------
    if (wid < 4) {
      int Mt = wid;
      int arow = Mt*16 + l15;
      half8 za[2];
#pragma unroll
      for (int c=0;c<2;++c){
        int slot = (c*4+l4) ^ (arow&7);
        za[c] = *(const half8*)&z1t[arow*64 + slot*8];
      }
      f32x4 acc={0.f,0.f,0.f,0.f};
      acc = MFMA16(za[0], W2f[0], acc);
      acc = MFMA16(za[1], W2f[1], acc);
      if (l15 < 4) {
#pragma unroll
        for (int r=0;r<4;++r){
          int row = Mt*16 + l4*4 + r;
          float d = acc[r] + b2l;
          d = fmaxf(d, 0.01f*d);
          dxdyt[row*4 + l15] = d;
        }
      }
    }
    __syncthreads();
    // ---------------- transform + outputs ----------------
    if (tid < 256) {
      int row = tid>>2, q = tid&3;
      size_t ob = (size_t)((size_t)t*B_TOT + b0 + row)*4;
      if (q < 2) {
        float dq  = dxdyt[row*4+q];
        float dq2 = dxdyt[row*4+q+2];
        float wh = obs_w * exp2f_(dq2 * 1.44269504f);
        float xn = obs_x + dq - 0.5f*wh;
        obs_x = xn; obs_w = wh;
        out0[ob + q]     = xn;
        out0[ob + q + 2] = wh;
        write_split(obsplit, row, q,   xn);
        write_split(obsplit, row, q+2, wh);
      } else {
        int c0 = (q-2)*2;
        float d0 = dxdyt[row*4+c0], d1 = dxdyt[row*4+c0+1];
        out1[ob + c0]     = d0;
        out1[ob + c0 + 1] = d1;
        write_split(obsplit, row, 4+c0, d0);
        write_split(obsplit, row, 5+c0, d1);
      }
    }
    __syncthreads();
  }
}

extern "C" void kernel_launch(void* const* d_in, const int* in_sizes, int n_in,
                              void* d_out, int out_size, void* d_ws, size_t ws_size,
                              hipStream_t stream) {
  const float* xy     = (const float*)d_in[0];
  const float* dxdy   = (const float*)d_in[1];
  const float* social = (const float*)d_in[2];
  const float* h0     = (const float*)d_in[3];
  // d_in[4] = pred_len (12, fixed by problem)
  const float* emb_W  = (const float*)d_in[5];
  const float* emb_b  = (const float*)d_in[6];
  const float* W_ih   = (const float*)d_in[7];
  const float* W_hh   = (const float*)d_in[8];
  const float* b_ih   = (const float*)d_in[9];
  const float* b_hh   = (const float*)d_in[10];
  const float* W1     = (const float*)d_in[11];
  const float* b1     = (const float*)d_in[12];
  const float* W2     = (const float*)d_in[13];
  const float* b2     = (const float*)d_in[14];

  half_t* wsh = (half_t*)d_ws;
  float*  wsf = (float*)((char*)d_ws + (size_t)HALFS_TOTAL*2);

  prep_kernel<<<(PREP_TOTAL+255)/256, 256, 0, stream>>>(
      emb_W, emb_b, W_ih, W_hh, b_ih, b_hh, W1, W2, b1, b2, wsh, wsf);
  decoder_kernel<<<NBLK, 512, 0, stream>>>(
      xy, dxdy, social, h0, wsh, wsf, (float*)d_out);
}